// Round 18
// baseline (151.500 us; speedup 1.0000x reference)
//
#include <hip/hip_runtime.h>
#include <hip/hip_bf16.h>
#include <cstddef>
#include <cstdint>

// Problem dims
constexpr int Bv = 128;   // batch
constexpr int Sv = 256;   // src len
constexpr int Hv = 1024;  // hidden
constexpr int Ev = 512;   // embed
constexpr int Vv = 32000; // vocab

typedef __attribute__((ext_vector_type(4))) float f32x4;
typedef __attribute__((ext_vector_type(8))) short short8;

// f32x4 -> 4 packed bf16 (RNE), via v_cvt_pk_bf16_f32.
__device__ __forceinline__ uint2 cvt4(float4 v) {
  union { __hip_bfloat162 b; unsigned u; } lo, hi;
  lo.b = __float22bfloat162_rn(float2{v.x, v.y});
  hi.b = __float22bfloat162_rn(float2{v.z, v.w});
  uint2 r;
  r.x = lo.u;
  r.y = hi.u;
  return r;
}
__device__ __forceinline__ unsigned short cvt1(float x) {
  union { __hip_bfloat16 b; unsigned short u; } c;
  c.b = __float2bfloat16(x);
  return c.u;
}

// ---------------------------------------------------------------------------
// MFMA GEMM with split-K partials (see earlier rounds for design notes).
// ABF16: A1 segment pre-converted bf16 (bit-identical). No cross-block
// atomics/fences (R10: agent-scope ACQ_REL per block = L2 writeback storm).
// ---------------------------------------------------------------------------
template <int BM, int BN, int BK, int SPLIT, int WTR, int GATHER, int ABF16,
          int MINW>
__global__ __launch_bounds__(256, MINW) void gemm_mfma(
    const int* __restrict__ ids,
    const float* __restrict__ A1, int lda1, int K1,
    const float* __restrict__ A2, int lda2, int K2,
    const float* __restrict__ W1, int ldw1,
    const float* __restrict__ W2, int ldw2,
    const float* __restrict__ bias1, const float* __restrict__ bias2,
    float* __restrict__ C, int ldc, int N) {
  constexpr int LP = BK + 8;       // LDS row pitch in bf16 (+8 pad)
  constexpr int KQ = BK / 4;       // 4-element chunks per row
  constexpr int KSUB = BK / 32;    // MFMA K-subtiles per iteration
  constexpr int WAVES_N = (BN >= 64) ? 2 : 1;
  constexpr int WAVES_M = 4 / WAVES_N;
  constexpr int WM = BM / WAVES_M;
  constexpr int FM = WM / 16;
  constexpr int FN = BN / (16 * WAVES_N);  // 32->2, 64->2, 128->4
  constexpr int WN = FN * 16;
  constexpr int ACH = (BM * BK) / (4 * 256);
  constexpr int WCH = (BN * BK) / (4 * 256);
  constexpr int WVN = WTR ? (BK * 8 / 256) : WCH;

  __shared__ unsigned short Al[BM * LP];
  __shared__ unsigned short Wl[BN * LP];

  const int tid = threadIdx.x;
  const int wid = tid >> 6, lane = tid & 63;
  const int nBlock = blockIdx.x * BN;
  const int mBlock = blockIdx.y * BM;
  const int z = blockIdx.z;
  int wm, wn;
  if (WAVES_N == 2) { wm = (wid >> 1) * WM; wn = (wid & 1) * WN; }
  else              { wm = wid * WM;        wn = 0; }

  float4 av[ACH];
  uint2  ab[ABF16 ? ACH : 1];
  float4 wv[WVN];
  bool   stagedBf = false;  // staged A regs are bf16 (ab) vs f32 (av)

  auto load_tile = [&](int kg) {
    const bool seg1 = kg < K1;
    const float* Wseg = seg1 ? W1 : W2;
    const int ldw = seg1 ? ldw1 : ldw2;
    const int kloc = seg1 ? kg : kg - K1;
    if (ABF16 && seg1) {
      stagedBf = true;
      const unsigned short* Ab = (const unsigned short*)A1;
#pragma unroll
      for (int i = 0; i < ACH; i++) {
        int c = tid + i * 256;
        int m = c / KQ, kq = (c % KQ) * 4;
        ab[i] = *(const uint2*)(Ab + (size_t)(mBlock + m) * lda1 + kloc + kq);
      }
    } else {
      stagedBf = false;
#pragma unroll
      for (int i = 0; i < ACH; i++) {
        int c = tid + i * 256;
        int m = c / KQ, kq = (c % KQ) * 4;
        const float* arow;
        if (seg1) {
          if (GATHER) arow = A1 + (size_t)ids[mBlock + m] * lda1;
          else        arow = A1 + (size_t)(mBlock + m) * lda1;
        } else {
          arow = A2 + (size_t)(mBlock + m) * lda2;
        }
        av[i] = *(const float4*)(arow + kloc + kq);
      }
    }
    if (WTR) {
#pragma unroll
      for (int i = 0; i < WVN; i++) {
        int c = tid + i * 256;           // BK k-rows x 8 n-quads
        int row = c >> 3, colq = c & 7;
        wv[i] = *(const float4*)(Wseg + (size_t)(kloc + row) * ldw + nBlock + colq * 4);
      }
    } else {
#pragma unroll
      for (int i = 0; i < WCH; i++) {
        int c = tid + i * 256;
        int n = c / KQ, kq = (c % KQ) * 4;
        wv[i] = *(const float4*)(Wseg + (size_t)(nBlock + n) * ldw + kloc + kq);
      }
    }
  };

  const int KT = K1 + K2;
  const int KS = KT / SPLIT;          // per-split K (multiple of BK; segment-aligned)
  const int kbeg = z * KS;
  const int NS = KS / BK;
  load_tile(kbeg);
  f32x4 acc[FM][FN] = {};

  for (int step = 0; step < NS; ++step) {
    __syncthreads();  // previous iteration's fragment reads done
    // commit regs -> LDS (identical uint2-per-chunk addressing, both paths)
#pragma unroll
    for (int i = 0; i < ACH; i++) {
      int c = tid + i * 256;
      int m = c / KQ, kq = (c % KQ) * 4;
      *(uint2*)&Al[m * LP + kq] = (ABF16 && stagedBf) ? ab[i] : cvt4(av[i]);
    }
    if (WTR) {
#pragma unroll
      for (int i = 0; i < WVN; i++) {
        int c = tid + i * 256;
        int row = c >> 3, colq = c & 7;
        Wl[(colq * 4 + 0) * LP + row] = cvt1(wv[i].x);
        Wl[(colq * 4 + 1) * LP + row] = cvt1(wv[i].y);
        Wl[(colq * 4 + 2) * LP + row] = cvt1(wv[i].z);
        Wl[(colq * 4 + 3) * LP + row] = cvt1(wv[i].w);
      }
    } else {
#pragma unroll
      for (int i = 0; i < WCH; i++) {
        int c = tid + i * 256;
        int n = c / KQ, kq = (c % KQ) * 4;
        *(uint2*)&Wl[n * LP + kq] = cvt4(wv[i]);
      }
    }
    __syncthreads();

    if (step + 1 < NS) load_tile(kbeg + (step + 1) * BK);  // prefetch

    const int klane = (lane >> 4) << 3;
    const int r = lane & 15;
    short8 af[KSUB][FM], wf[KSUB][FN];
#pragma unroll
    for (int ks = 0; ks < KSUB; ks++) {
#pragma unroll
      for (int f = 0; f < FM; f++)
        af[ks][f] = *(const short8*)&Al[(wm + f * 16 + r) * LP + ks * 32 + klane];
#pragma unroll
      for (int f = 0; f < FN; f++)
        wf[ks][f] = *(const short8*)&Wl[(wn + f * 16 + r) * LP + ks * 32 + klane];
    }
#pragma unroll
    for (int ks = 0; ks < KSUB; ks++)
#pragma unroll
      for (int fm = 0; fm < FM; fm++)
#pragma unroll
        for (int fn = 0; fn < FN; fn++)
          acc[fm][fn] = __builtin_amdgcn_mfma_f32_16x16x32_bf16(
              af[ks][fm], wf[ks][fn], acc[fm][fn], 0, 0, 0);
  }

  // Epilogue. D layout: col = lane&15, row = (lane>>4)*4 + j
  float* Cp = C + (size_t)z * gridDim.y * BM * ldc;
  const int col = lane & 15, rb = (lane >> 4) << 2;
#pragma unroll
  for (int fn = 0; fn < FN; fn++) {
    int n = nBlock + wn + fn * 16 + col;
    float bsum = 0.f;
    if (z == 0) {
      if (bias1) bsum += bias1[n];
      if (bias2) bsum += bias2[n];
    }
#pragma unroll
    for (int fm = 0; fm < FM; fm++) {
#pragma unroll
      for (int j = 0; j < 4; j++) {
        int m = mBlock + wm + fm * 16 + rb + j;
        Cp[(size_t)m * ldc + n] = acc[fm][fn][j] + bsum;
      }
    }
  }
}

// ---------------------------------------------------------------------------
// LSTM pointwise; also emits h as bf16 for downstream GEMM A-sides.
template <int P>
__global__ void lstm_pw(const float* __restrict__ Gp,
                        const float* __restrict__ c_prev,
                        float* __restrict__ h_out,
                        float* __restrict__ c_out,
                        unsigned short* __restrict__ h_bf) {
  int i4 = blockIdx.x * 256 + threadIdx.x;  // 32768 float4 slots (B*H/4)
  int b = i4 >> 8, j4 = i4 & 255;
  float4 gi{}, gf{}, gg{}, go{};
#pragma unroll
  for (int p = 0; p < P; p++) {
    const float4* g = (const float4*)(Gp + (size_t)p * Bv * 4 * Hv + (size_t)b * 4096);
    float4 a = g[j4], bb = g[256 + j4], c = g[512 + j4], d = g[768 + j4];
    gi.x += a.x; gi.y += a.y; gi.z += a.z; gi.w += a.w;
    gf.x += bb.x; gf.y += bb.y; gf.z += bb.z; gf.w += bb.w;
    gg.x += c.x; gg.y += c.y; gg.z += c.z; gg.w += c.w;
    go.x += d.x; go.y += d.y; go.z += d.z; go.w += d.w;
  }
  float4 c4 = ((const float4*)c_prev)[i4];
  float4 h4, cn4;
  float* gip = &gi.x; float* gfp = &gf.x; float* ggp = &gg.x; float* gop = &go.x;
  float* cp = &c4.x; float* hp = &h4.x; float* cnp = &cn4.x;
#pragma unroll
  for (int u = 0; u < 4; u++) {
    float si = 1.f / (1.f + expf(-gip[u]));
    float sf = 1.f / (1.f + expf(-gfp[u]));
    float so = 1.f / (1.f + expf(-gop[u]));
    float cn = sf * cp[u] + si * tanhf(ggp[u]);
    hp[u] = so * tanhf(cn);
    cnp[u] = cn;
  }
  ((float4*)h_out)[i4] = h4;
  ((float4*)c_out)[i4] = cn4;
  *(uint2*)&h_bf[(size_t)i4 * 4] = cvt4(h4);
}

// ---------------------------------------------------------------------------
// Fused attention pass 1 (see R13/R14 notes): grid (128 b, 16 chunks),
// 2048 blocks; enc read from HBM exactly once.
__global__ __launch_bounds__(256) void attn_part(
    const float* __restrict__ enc, const float* __restrict__ qp,
    float* __restrict__ numb, float2* __restrict__ mden) {
  const int b = blockIdx.x, ch = blockIdx.y;
  const int t = threadIdx.x, lane = t & 63, wid = t >> 6;
  const int sbase = ch * 16;
  __shared__ float qs[1024];
  __shared__ float es[16], ee[16];
  {
    const float4* q0 = (const float4*)(qp + (size_t)b * Hv);
    const float4* q1 = (const float4*)(qp + 1 * Bv * Hv + (size_t)b * Hv);
    const float4* q2 = (const float4*)(qp + 2 * Bv * Hv + (size_t)b * Hv);
    const float4* q3 = (const float4*)(qp + 3 * Bv * Hv + (size_t)b * Hv);
    float4 a = q0[t], bq = q1[t], c = q2[t], d = q3[t];
    float4 s;
    s.x = a.x + bq.x + c.x + d.x; s.y = a.y + bq.y + c.y + d.y;
    s.z = a.z + bq.z + c.z + d.z; s.w = a.w + bq.w + c.w + d.w;
    ((float4*)qs)[t] = s;
  }
  __syncthreads();

  const float4* q4 = (const float4*)qs;
#pragma unroll
  for (int i = 0; i < 4; i++) {
    int sl = wid * 4 + i;
    const float4* e4 = (const float4*)(enc + ((size_t)(sbase + sl) * Bv + b) * Hv);
    float sum = 0.f;
#pragma unroll
    for (int j = 0; j < 4; j++) {
      int idx = lane + j * 64;
      float4 e = e4[idx], qq = q4[idx];
      sum += e.x * qq.x + e.y * qq.y + e.z * qq.z + e.w * qq.w;
    }
#pragma unroll
    for (int o = 32; o; o >>= 1) sum += __shfl_xor(sum, o);
    if (lane == 0) es[sl] = sum;
  }
  __syncthreads();

  float m = es[0];
#pragma unroll
  for (int i = 1; i < 16; i++) m = fmaxf(m, es[i]);
  if (t < 16) ee[t] = expf(es[t] - m);
  __syncthreads();
  if (t == 0) {
    float den = 0.f;
#pragma unroll
    for (int i = 0; i < 16; i++) den += ee[i];
    mden[b * 16 + ch] = make_float2(m, den);
  }

  float4 acc = make_float4(0.f, 0.f, 0.f, 0.f);
  const float* ebase = enc + ((size_t)sbase * Bv + b) * Hv + t * 4;
#pragma unroll
  for (int s = 0; s < 16; s++) {
    float4 e = *(const float4*)(ebase + (size_t)s * Bv * Hv);
    float w = ee[s];
    acc.x += w * e.x; acc.y += w * e.y; acc.z += w * e.z; acc.w += w * e.w;
  }
  *(float4*)(numb + ((size_t)b * 16 + ch) * Hv + t * 4) = acc;
}

// ---------------------------------------------------------------------------
// Pass 2: exact recombination over the 16 chunks -> ctx.
__global__ __launch_bounds__(256) void attn_fin(
    const float* __restrict__ numb, const float2* __restrict__ mden,
    float* __restrict__ ctx) {
  const int b = blockIdx.x, t = threadIdx.x;
  float mv[16], dv[16];
  float M = -3.4e38f;
#pragma unroll
  for (int c = 0; c < 16; c++) {
    float2 md = mden[b * 16 + c];
    mv[c] = md.x; dv[c] = md.y;
    M = fmaxf(M, md.x);
  }
  float den = 0.f, sc[16];
#pragma unroll
  for (int c = 0; c < 16; c++) {
    sc[c] = expf(mv[c] - M);
    den += sc[c] * dv[c];
  }
  float inv = 1.f / den;
  float4 r = make_float4(0.f, 0.f, 0.f, 0.f);
#pragma unroll
  for (int c = 0; c < 16; c++) {
    float4 n = *(const float4*)(numb + ((size_t)b * 16 + c) * Hv + t * 4);
    float s = sc[c];
    r.x += s * n.x; r.y += s * n.y; r.z += s * n.z; r.w += s * n.w;
  }
  r.x *= inv; r.y *= inv; r.z *= inv; r.w *= inv;
  *(float4*)(ctx + (size_t)b * Hv + t * 4) = r;
}

// ---------------------------------------------------------------------------
// cat = tanh(sum of P partials) -> bf16 (bit-identical to GEMM's cvt).
template <int P>
__global__ void finish_cat(const float* __restrict__ catp,
                           unsigned short* __restrict__ catb) {
  int i4 = blockIdx.x * 256 + threadIdx.x;  // 32768 slots of 4
  constexpr int ST = Bv * Hv / 4;
  const float4* p = (const float4*)catp;
  float4 s = p[i4];
#pragma unroll
  for (int q = 1; q < P; q++) {
    float4 v = p[(size_t)q * ST + i4];
    s.x += v.x; s.y += v.y; s.z += v.z; s.w += v.w;
  }
  float4 r;
  r.x = tanhf(s.x); r.y = tanhf(s.y); r.z = tanhf(s.z); r.w = tanhf(s.w);
  *(uint2*)&catb[(size_t)i4 * 4] = cvt4(r);
}

// ---------------------------------------------------------------------------
extern "C" void kernel_launch(void* const* d_in, const int* in_sizes, int n_in,
                              void* d_out, int out_size, void* d_ws,
                              size_t ws_size, hipStream_t stream) {
  const int*   ids      = (const int*)d_in[0];
  const float* h0       = (const float*)d_in[1];
  const float* c0       = (const float*)d_in[2];
  const float* enc      = (const float*)d_in[3];
  const float* emb      = (const float*)d_in[4];
  const float* w_ih0    = (const float*)d_in[5];
  const float* w_hh0    = (const float*)d_in[6];
  const float* b_ih0    = (const float*)d_in[7];
  const float* b_hh0    = (const float*)d_in[8];
  const float* w_ih1    = (const float*)d_in[9];
  const float* w_hh1    = (const float*)d_in[10];
  const float* b_ih1    = (const float*)d_in[11];
  const float* b_hh1    = (const float*)d_in[12];
  const float* attn_w   = (const float*)d_in[13];
  const float* attn_b   = (const float*)d_in[14];  // cancels in softmax
  const float* concat_w = (const float*)d_in[15];
  const float* concat_b = (const float*)d_in[16];
  const float* out_w    = (const float*)d_in[17];
  const float* out_b    = (const float*)d_in[18];
  (void)attn_b;

  float* logits = (float*)d_out;                  // [128, 32000]
  float* hout   = logits + (size_t)Bv * Vv;       // [2, 128, 1024]
  float* cout   = hout + 2 * Bv * Hv;             // [2, 128, 1024]

  float* ws = (float*)d_ws;
  // High-split layout needs (14*524288 + 4*131072 + 8*131072 + 131072) f32
  // + 3*131072 bf16 ≈ 37 MB. Guard on ws_size; else use the proven R17 path.
  const size_t need_hi =
      ((size_t)14 * 524288 + 13 * 131072) * 4 + (size_t)3 * 131072 * 2;
  const bool hi = ws_size >= need_hi;

  if (hi) {
    float* G0p  = ws;                        // 6 * 524288
    float* G1p  = G0p + 6 * (size_t)524288;  // 8 * 524288
    float* qp   = G1p + 8 * (size_t)524288;  // 4 * 131072
    float* catp = qp + 4 * 131072;           // 8 * 131072
    float* ctx  = catp + 8 * 131072;         // 131072
    unsigned short* catb = (unsigned short*)(ctx + 131072);
    unsigned short* hbf0 = catb + 131072;
    unsigned short* hbf1 = hbf0 + 131072;
    float* numb = G1p;                       // reuses G1p (dead after pw1)
    float2* mden = (float2*)G0p;             // reuses G0p (dead after pw0)

    // 1. LSTM0 gates: SPLIT=6 (KS=256, NS=4), 1536 blocks
    gemm_mfma<64, 32, 64, 6, 0, 1, 0, 4><<<dim3(128, 2, 6), 256, 0, stream>>>(
        ids, emb, Ev, Ev, h0, Hv, Hv, w_ih0, Ev, w_hh0, Hv, b_ih0, b_hh0,
        G0p, 4 * Hv, 4 * Hv);
    // 2. LSTM0 pointwise (sums 6)
    lstm_pw<6><<<128, 256, 0, stream>>>(G0p, c0, hout, cout, hbf0);
    // 3. LSTM1 gates: SPLIT=8 (KS=256, NS=4), 2048 blocks; A1 bf16
    gemm_mfma<64, 32, 64, 8, 0, 0, 1, 4><<<dim3(128, 2, 8), 256, 0, stream>>>(
        nullptr, (const float*)hbf0, Hv, Hv, h0 + Bv * Hv, Hv, Hv,
        w_ih1, Hv, w_hh1, Hv, b_ih1, b_hh1, G1p, 4 * Hv, 4 * Hv);
    // 4. LSTM1 pointwise (sums 8)
    lstm_pw<8><<<128, 256, 0, stream>>>(G1p, c0 + Bv * Hv, hout + Bv * Hv,
                                        cout + Bv * Hv, hbf1);
    // 5. q = rnn @ attn_w (WTR), SPLIT=4 (attn_part sums 4 partials)
    gemm_mfma<64, 32, 64, 4, 1, 0, 1, 4><<<dim3(32, 2, 4), 256, 0, stream>>>(
        nullptr, (const float*)hbf1, Hv, Hv, nullptr, 0, 0, attn_w, Hv,
        nullptr, 0, nullptr, nullptr, qp, Hv, Hv);
    // 6-7. fused attention
    attn_part<<<dim3(128, 16), 256, 0, stream>>>(enc, qp, numb, mden);
    attn_fin<<<128, 256, 0, stream>>>(numb, mden, ctx);
    // 8. concat gates: SPLIT=8 (KS=256, NS=4), 512 blocks
    gemm_mfma<64, 32, 64, 8, 0, 0, 1, 4><<<dim3(32, 2, 8), 256, 0, stream>>>(
        nullptr, (const float*)hbf1, Hv, Hv, ctx, Hv, Hv, concat_w, 2 * Hv,
        concat_w + Hv, 2 * Hv, concat_b, nullptr, catp, Hv, Hv);
    // 9. cat = tanh(sum of 8) -> bf16
    finish_cat<8><<<128, 256, 0, stream>>>(catp, catb);
    // 10. logits: BM=128/BN=64, (500,1), out_w read exactly once, A bf16
    gemm_mfma<128, 64, 64, 1, 0, 0, 1, 2><<<dim3(500, 1, 1), 256, 0, stream>>>(
        nullptr, (const float*)catb, Hv, Hv, nullptr, 0, 0, out_w, Hv,
        nullptr, 0, out_b, nullptr, logits, Vv, Vv);
  } else {
    // R17 fallback (proven 145.6 us)
    float* G0p  = ws;
    float* G1p  = G0p + 3 * 524288;
    float* qp   = G1p + 4 * (size_t)524288;
    float* catp = qp + 4 * 131072;
    float* ctx  = catp + 4 * 131072;
    unsigned short* catb = (unsigned short*)(ctx + 131072);
    unsigned short* hbf0 = catb + 131072;
    unsigned short* hbf1 = hbf0 + 131072;
    float* numb = G1p;
    float2* mden = (float2*)G0p;

    gemm_mfma<64, 32, 64, 3, 0, 1, 0, 4><<<dim3(128, 2, 3), 256, 0, stream>>>(
        ids, emb, Ev, Ev, h0, Hv, Hv, w_ih0, Ev, w_hh0, Hv, b_ih0, b_hh0,
        G0p, 4 * Hv, 4 * Hv);
    lstm_pw<3><<<128, 256, 0, stream>>>(G0p, c0, hout, cout, hbf0);
    gemm_mfma<64, 32, 64, 4, 0, 0, 1, 4><<<dim3(128, 2, 4), 256, 0, stream>>>(
        nullptr, (const float*)hbf0, Hv, Hv, h0 + Bv * Hv, Hv, Hv,
        w_ih1, Hv, w_hh1, Hv, b_ih1, b_hh1, G1p, 4 * Hv, 4 * Hv);
    lstm_pw<4><<<128, 256, 0, stream>>>(G1p, c0 + Bv * Hv, hout + Bv * Hv,
                                        cout + Bv * Hv, hbf1);
    gemm_mfma<64, 32, 64, 4, 1, 0, 1, 4><<<dim3(32, 2, 4), 256, 0, stream>>>(
        nullptr, (const float*)hbf1, Hv, Hv, nullptr, 0, 0, attn_w, Hv,
        nullptr, 0, nullptr, nullptr, qp, Hv, Hv);
    attn_part<<<dim3(128, 16), 256, 0, stream>>>(enc, qp, numb, mden);
    attn_fin<<<128, 256, 0, stream>>>(numb, mden, ctx);
    gemm_mfma<64, 32, 64, 4, 0, 0, 1, 4><<<dim3(32, 2, 4), 256, 0, stream>>>(
        nullptr, (const float*)hbf1, Hv, Hv, ctx, Hv, Hv, concat_w, 2 * Hv,
        concat_w + Hv, 2 * Hv, concat_b, nullptr, catp, Hv, Hv);
    finish_cat<4><<<128, 256, 0, stream>>>(catp, catb);
    gemm_mfma<128, 64, 64, 1, 0, 0, 1, 2><<<dim3(500, 1, 1), 256, 0, stream>>>(
        nullptr, (const float*)catb, Hv, Hv, nullptr, 0, 0, out_w, Hv,
        nullptr, 0, out_b, nullptr, logits, Vv, Vv);
  }
}

// Round 19
// 144.472 us; speedup vs baseline: 1.0486x; 1.0486x over previous
//
#include <hip/hip_runtime.h>
#include <hip/hip_bf16.h>
#include <cstddef>
#include <cstdint>

// Problem dims
constexpr int Bv = 128;   // batch
constexpr int Sv = 256;   // src len
constexpr int Hv = 1024;  // hidden
constexpr int Ev = 512;   // embed
constexpr int Vv = 32000; // vocab

typedef __attribute__((ext_vector_type(4))) float f32x4;
typedef __attribute__((ext_vector_type(8))) short short8;

// f32x4 -> 4 packed bf16 (RNE), via v_cvt_pk_bf16_f32.
__device__ __forceinline__ uint2 cvt4(float4 v) {
  union { __hip_bfloat162 b; unsigned u; } lo, hi;
  lo.b = __float22bfloat162_rn(float2{v.x, v.y});
  hi.b = __float22bfloat162_rn(float2{v.z, v.w});
  uint2 r;
  r.x = lo.u;
  r.y = hi.u;
  return r;
}
__device__ __forceinline__ unsigned short cvt1(float x) {
  union { __hip_bfloat16 b; unsigned short u; } c;
  c.b = __float2bfloat16(x);
  return c.u;
}

// ---------------------------------------------------------------------------
// MFMA GEMM with split-K partials:
//   Cp[z][m,n] = sum_{k in split z} A[m,k]*W[n,k]  (+bias on z==0)
// A = A1 (k<K1, optionally gathered emb rows) then A2. W row-major [N,K]
// unless WTR (W1 is [K,N], transposed during LDS staging; needs BN==32).
// ABF16: A1 is bf16 row-major (pre-converted, bit-identical to in-GEMM cvt);
//   applies to the A1 SEGMENT only -- A2 stays f32+cvt. LDS commit
//   addressing identical in both paths (R6's regression was addressing).
// BK: K-tile per iteration. Bigger BK = more loads in flight per wave.
// Partial z written at C + z*gridDim.y*BM*ldc. Consumers sum partials.
// NOTE (R10 lesson): no cross-block atomics/fences — agent-scope ACQ_REL
// per block on 8-XCD forces L2 writeback storms (17x slowdown).
// SPLIT tuning (R18 lesson): SPLIT=3/4 is the optimum; higher splits pay
// more partial-buffer traffic than the latency hiding returns.
// ---------------------------------------------------------------------------
template <int BM, int BN, int BK, int SPLIT, int WTR, int GATHER, int ABF16,
          int MINW>
__global__ __launch_bounds__(256, MINW) void gemm_mfma(
    const int* __restrict__ ids,
    const float* __restrict__ A1, int lda1, int K1,
    const float* __restrict__ A2, int lda2, int K2,
    const float* __restrict__ W1, int ldw1,
    const float* __restrict__ W2, int ldw2,
    const float* __restrict__ bias1, const float* __restrict__ bias2,
    float* __restrict__ C, int ldc, int N) {
  constexpr int LP = BK + 8;       // LDS row pitch in bf16 (+8 pad)
  constexpr int KQ = BK / 4;       // 4-element chunks per row
  constexpr int KSUB = BK / 32;    // MFMA K-subtiles per iteration
  constexpr int WAVES_N = (BN >= 64) ? 2 : 1;
  constexpr int WAVES_M = 4 / WAVES_N;
  constexpr int WM = BM / WAVES_M;
  constexpr int FM = WM / 16;
  constexpr int FN = BN / (16 * WAVES_N);  // 32->2, 64->2, 128->4
  constexpr int WN = FN * 16;
  constexpr int ACH = (BM * BK) / (4 * 256);
  constexpr int WCH = (BN * BK) / (4 * 256);
  constexpr int WVN = WTR ? (BK * 8 / 256) : WCH;

  __shared__ unsigned short Al[BM * LP];
  __shared__ unsigned short Wl[BN * LP];

  const int tid = threadIdx.x;
  const int wid = tid >> 6, lane = tid & 63;
  const int nBlock = blockIdx.x * BN;
  const int mBlock = blockIdx.y * BM;
  const int z = blockIdx.z;
  int wm, wn;
  if (WAVES_N == 2) { wm = (wid >> 1) * WM; wn = (wid & 1) * WN; }
  else              { wm = wid * WM;        wn = 0; }

  float4 av[ACH];
  uint2  ab[ABF16 ? ACH : 1];
  float4 wv[WVN];
  bool   stagedBf = false;  // staged A regs are bf16 (ab) vs f32 (av)

  auto load_tile = [&](int kg) {
    const bool seg1 = kg < K1;
    const float* Wseg = seg1 ? W1 : W2;
    const int ldw = seg1 ? ldw1 : ldw2;
    const int kloc = seg1 ? kg : kg - K1;
    if (ABF16 && seg1) {
      stagedBf = true;
      const unsigned short* Ab = (const unsigned short*)A1;
#pragma unroll
      for (int i = 0; i < ACH; i++) {
        int c = tid + i * 256;
        int m = c / KQ, kq = (c % KQ) * 4;
        ab[i] = *(const uint2*)(Ab + (size_t)(mBlock + m) * lda1 + kloc + kq);
      }
    } else {
      stagedBf = false;
#pragma unroll
      for (int i = 0; i < ACH; i++) {
        int c = tid + i * 256;
        int m = c / KQ, kq = (c % KQ) * 4;
        const float* arow;
        if (seg1) {
          if (GATHER) arow = A1 + (size_t)ids[mBlock + m] * lda1;
          else        arow = A1 + (size_t)(mBlock + m) * lda1;
        } else {
          arow = A2 + (size_t)(mBlock + m) * lda2;
        }
        av[i] = *(const float4*)(arow + kloc + kq);
      }
    }
    if (WTR) {
#pragma unroll
      for (int i = 0; i < WVN; i++) {
        int c = tid + i * 256;           // BK k-rows x 8 n-quads
        int row = c >> 3, colq = c & 7;
        wv[i] = *(const float4*)(Wseg + (size_t)(kloc + row) * ldw + nBlock + colq * 4);
      }
    } else {
#pragma unroll
      for (int i = 0; i < WCH; i++) {
        int c = tid + i * 256;
        int n = c / KQ, kq = (c % KQ) * 4;
        wv[i] = *(const float4*)(Wseg + (size_t)(nBlock + n) * ldw + kloc + kq);
      }
    }
  };

  const int KT = K1 + K2;
  const int KS = KT / SPLIT;          // per-split K (multiple of BK; segment-aligned)
  const int kbeg = z * KS;
  const int NS = KS / BK;
  load_tile(kbeg);
  f32x4 acc[FM][FN] = {};

  for (int step = 0; step < NS; ++step) {
    __syncthreads();  // previous iteration's fragment reads done
    // commit regs -> LDS (identical uint2-per-chunk addressing, both paths)
#pragma unroll
    for (int i = 0; i < ACH; i++) {
      int c = tid + i * 256;
      int m = c / KQ, kq = (c % KQ) * 4;
      *(uint2*)&Al[m * LP + kq] = (ABF16 && stagedBf) ? ab[i] : cvt4(av[i]);
    }
    if (WTR) {
#pragma unroll
      for (int i = 0; i < WVN; i++) {
        int c = tid + i * 256;
        int row = c >> 3, colq = c & 7;
        Wl[(colq * 4 + 0) * LP + row] = cvt1(wv[i].x);
        Wl[(colq * 4 + 1) * LP + row] = cvt1(wv[i].y);
        Wl[(colq * 4 + 2) * LP + row] = cvt1(wv[i].z);
        Wl[(colq * 4 + 3) * LP + row] = cvt1(wv[i].w);
      }
    } else {
#pragma unroll
      for (int i = 0; i < WCH; i++) {
        int c = tid + i * 256;
        int n = c / KQ, kq = (c % KQ) * 4;
        *(uint2*)&Wl[n * LP + kq] = cvt4(wv[i]);
      }
    }
    __syncthreads();

    if (step + 1 < NS) load_tile(kbeg + (step + 1) * BK);  // prefetch

    const int klane = (lane >> 4) << 3;
    const int r = lane & 15;
    short8 af[KSUB][FM], wf[KSUB][FN];
#pragma unroll
    for (int ks = 0; ks < KSUB; ks++) {
#pragma unroll
      for (int f = 0; f < FM; f++)
        af[ks][f] = *(const short8*)&Al[(wm + f * 16 + r) * LP + ks * 32 + klane];
#pragma unroll
      for (int f = 0; f < FN; f++)
        wf[ks][f] = *(const short8*)&Wl[(wn + f * 16 + r) * LP + ks * 32 + klane];
    }
#pragma unroll
    for (int ks = 0; ks < KSUB; ks++)
#pragma unroll
      for (int fm = 0; fm < FM; fm++)
#pragma unroll
        for (int fn = 0; fn < FN; fn++)
          acc[fm][fn] = __builtin_amdgcn_mfma_f32_16x16x32_bf16(
              af[ks][fm], wf[ks][fn], acc[fm][fn], 0, 0, 0);
  }

  // Epilogue. D layout: col = lane&15, row = (lane>>4)*4 + j
  float* Cp = C + (size_t)z * gridDim.y * BM * ldc;
  const int col = lane & 15, rb = (lane >> 4) << 2;
#pragma unroll
  for (int fn = 0; fn < FN; fn++) {
    int n = nBlock + wn + fn * 16 + col;
    float bsum = 0.f;
    if (z == 0) {
      if (bias1) bsum += bias1[n];
      if (bias2) bsum += bias2[n];
    }
#pragma unroll
    for (int fm = 0; fm < FM; fm++) {
#pragma unroll
      for (int j = 0; j < 4; j++) {
        int m = mBlock + wm + fm * 16 + rb + j;
        Cp[(size_t)m * ldc + n] = acc[fm][fn][j] + bsum;
      }
    }
  }
}

// ---------------------------------------------------------------------------
// LSTM pointwise; also emits h as bf16 for downstream GEMM A-sides
// (bit-identical to their internal cvt).
template <int P>
__global__ void lstm_pw(const float* __restrict__ Gp,
                        const float* __restrict__ c_prev,
                        float* __restrict__ h_out,
                        float* __restrict__ c_out,
                        unsigned short* __restrict__ h_bf) {
  int i4 = blockIdx.x * 256 + threadIdx.x;  // 32768 float4 slots (B*H/4)
  int b = i4 >> 8, j4 = i4 & 255;
  float4 gi{}, gf{}, gg{}, go{};
#pragma unroll
  for (int p = 0; p < P; p++) {
    const float4* g = (const float4*)(Gp + (size_t)p * Bv * 4 * Hv + (size_t)b * 4096);
    float4 a = g[j4], bb = g[256 + j4], c = g[512 + j4], d = g[768 + j4];
    gi.x += a.x; gi.y += a.y; gi.z += a.z; gi.w += a.w;
    gf.x += bb.x; gf.y += bb.y; gf.z += bb.z; gf.w += bb.w;
    gg.x += c.x; gg.y += c.y; gg.z += c.z; gg.w += c.w;
    go.x += d.x; go.y += d.y; go.z += d.z; go.w += d.w;
  }
  float4 c4 = ((const float4*)c_prev)[i4];
  float4 h4, cn4;
  float* gip = &gi.x; float* gfp = &gf.x; float* ggp = &gg.x; float* gop = &go.x;
  float* cp = &c4.x; float* hp = &h4.x; float* cnp = &cn4.x;
#pragma unroll
  for (int u = 0; u < 4; u++) {
    float si = 1.f / (1.f + expf(-gip[u]));
    float sf = 1.f / (1.f + expf(-gfp[u]));
    float so = 1.f / (1.f + expf(-gop[u]));
    float cn = sf * cp[u] + si * tanhf(ggp[u]);
    hp[u] = so * tanhf(cn);
    cnp[u] = cn;
  }
  ((float4*)h_out)[i4] = h4;
  ((float4*)c_out)[i4] = cn4;
  *(uint2*)&h_bf[(size_t)i4 * 4] = cvt4(h4);
}

// ---------------------------------------------------------------------------
// Fused attention pass 1, chunked for TLP. Grid (128 b, 16 chunks of 16 s),
// 2048 blocks (~8/CU). Per block: q[b] (sum of 4 split-K partials) -> LDS;
// 16 scores (4 wave-dots per wave); chunk-local max/exp/denominator;
// partial numerator over 16 rows, whole block on the same s-row (L2-hot).
// enc read from HBM exactly once across the grid.
__global__ __launch_bounds__(256) void attn_part(
    const float* __restrict__ enc, const float* __restrict__ qp,
    float* __restrict__ numb, float2* __restrict__ mden) {
  const int b = blockIdx.x, ch = blockIdx.y;
  const int t = threadIdx.x, lane = t & 63, wid = t >> 6;
  const int sbase = ch * 16;
  __shared__ float qs[1024];
  __shared__ float es[16], ee[16];
  {
    const float4* q0 = (const float4*)(qp + (size_t)b * Hv);
    const float4* q1 = (const float4*)(qp + 1 * Bv * Hv + (size_t)b * Hv);
    const float4* q2 = (const float4*)(qp + 2 * Bv * Hv + (size_t)b * Hv);
    const float4* q3 = (const float4*)(qp + 3 * Bv * Hv + (size_t)b * Hv);
    float4 a = q0[t], bq = q1[t], c = q2[t], d = q3[t];
    float4 s;
    s.x = a.x + bq.x + c.x + d.x; s.y = a.y + bq.y + c.y + d.y;
    s.z = a.z + bq.z + c.z + d.z; s.w = a.w + bq.w + c.w + d.w;
    ((float4*)qs)[t] = s;
  }
  __syncthreads();

  // scores: wave wid covers local s = wid*4 .. wid*4+3
  const float4* q4 = (const float4*)qs;
#pragma unroll
  for (int i = 0; i < 4; i++) {
    int sl = wid * 4 + i;
    const float4* e4 = (const float4*)(enc + ((size_t)(sbase + sl) * Bv + b) * Hv);
    float sum = 0.f;
#pragma unroll
    for (int j = 0; j < 4; j++) {
      int idx = lane + j * 64;
      float4 e = e4[idx], qq = q4[idx];
      sum += e.x * qq.x + e.y * qq.y + e.z * qq.z + e.w * qq.w;
    }
#pragma unroll
    for (int o = 32; o; o >>= 1) sum += __shfl_xor(sum, o);
    if (lane == 0) es[sl] = sum;
  }
  __syncthreads();

  // chunk-local softmax pieces
  float m = es[0];
#pragma unroll
  for (int i = 1; i < 16; i++) m = fmaxf(m, es[i]);
  if (t < 16) ee[t] = expf(es[t] - m);
  __syncthreads();
  if (t == 0) {
    float den = 0.f;
#pragma unroll
    for (int i = 0; i < 16; i++) den += ee[i];
    mden[b * 16 + ch] = make_float2(m, den);
  }

  // partial numerator: thread t owns h = t*4..+3; whole block walks the
  // same s-row together (4 KB coalesced per iteration, L2-hot rows).
  float4 acc = make_float4(0.f, 0.f, 0.f, 0.f);
  const float* ebase = enc + ((size_t)sbase * Bv + b) * Hv + t * 4;
#pragma unroll
  for (int s = 0; s < 16; s++) {
    float4 e = *(const float4*)(ebase + (size_t)s * Bv * Hv);
    float w = ee[s];
    acc.x += w * e.x; acc.y += w * e.y; acc.z += w * e.z; acc.w += w * e.w;
  }
  *(float4*)(numb + ((size_t)b * 16 + ch) * Hv + t * 4) = acc;
}

// ---------------------------------------------------------------------------
// Pass 2: exact recombination over the 16 chunks -> ctx.
__global__ __launch_bounds__(256) void attn_fin(
    const float* __restrict__ numb, const float2* __restrict__ mden,
    float* __restrict__ ctx) {
  const int b = blockIdx.x, t = threadIdx.x;
  float mv[16], dv[16];
  float M = -3.4e38f;
#pragma unroll
  for (int c = 0; c < 16; c++) {
    float2 md = mden[b * 16 + c];
    mv[c] = md.x; dv[c] = md.y;
    M = fmaxf(M, md.x);
  }
  float den = 0.f, sc[16];
#pragma unroll
  for (int c = 0; c < 16; c++) {
    sc[c] = expf(mv[c] - M);
    den += sc[c] * dv[c];
  }
  float inv = 1.f / den;
  float4 r = make_float4(0.f, 0.f, 0.f, 0.f);
#pragma unroll
  for (int c = 0; c < 16; c++) {
    float4 n = *(const float4*)(numb + ((size_t)b * 16 + c) * Hv + t * 4);
    float s = sc[c];
    r.x += s * n.x; r.y += s * n.y; r.z += s * n.z; r.w += s * n.w;
  }
  r.x *= inv; r.y *= inv; r.z *= inv; r.w *= inv;
  *(float4*)(ctx + (size_t)b * Hv + t * 4) = r;
}

// ---------------------------------------------------------------------------
// cat = tanh(sum of 4 partials), stored bf16 (sole consumer is the logits
// GEMM, which converted to bf16 anyway -- bit-identical, halves A traffic).
__global__ void finish_cat(const float* __restrict__ catp,
                           unsigned short* __restrict__ catb) {
  int i4 = blockIdx.x * 256 + threadIdx.x;  // 32768 slots of 4
  constexpr int ST = Bv * Hv / 4;
  const float4* p = (const float4*)catp;
  float4 a = p[i4], b = p[ST + i4], c = p[2 * ST + i4], d = p[3 * ST + i4];
  float4 r;
  r.x = tanhf(a.x + b.x + c.x + d.x);
  r.y = tanhf(a.y + b.y + c.y + d.y);
  r.z = tanhf(a.z + b.z + c.z + d.z);
  r.w = tanhf(a.w + b.w + c.w + d.w);
  *(uint2*)&catb[(size_t)i4 * 4] = cvt4(r);
}

// ---------------------------------------------------------------------------
extern "C" void kernel_launch(void* const* d_in, const int* in_sizes, int n_in,
                              void* d_out, int out_size, void* d_ws,
                              size_t ws_size, hipStream_t stream) {
  const int*   ids      = (const int*)d_in[0];
  const float* h0       = (const float*)d_in[1];
  const float* c0       = (const float*)d_in[2];
  const float* enc      = (const float*)d_in[3];
  const float* emb      = (const float*)d_in[4];
  const float* w_ih0    = (const float*)d_in[5];
  const float* w_hh0    = (const float*)d_in[6];
  const float* b_ih0    = (const float*)d_in[7];
  const float* b_hh0    = (const float*)d_in[8];
  const float* w_ih1    = (const float*)d_in[9];
  const float* w_hh1    = (const float*)d_in[10];
  const float* b_ih1    = (const float*)d_in[11];
  const float* b_hh1    = (const float*)d_in[12];
  const float* attn_w   = (const float*)d_in[13];
  const float* attn_b   = (const float*)d_in[14];  // cancels in softmax
  const float* concat_w = (const float*)d_in[15];
  const float* concat_b = (const float*)d_in[16];
  const float* out_w    = (const float*)d_in[17];
  const float* out_b    = (const float*)d_in[18];
  (void)attn_b;

  float* logits = (float*)d_out;                  // [128, 32000]
  float* hout   = logits + (size_t)Bv * Vv;       // [2, 128, 1024]
  float* cout   = hout + 2 * Bv * Hv;             // [2, 128, 1024]

  float* ws   = (float*)d_ws;
  float* G0p  = ws;                       // 3 * 524288 (dead after step 2)
  float* G1p  = G0p + 3 * 524288;         // 4 * 524288 (dead after step 4)
  float* qp   = G1p + 4 * (size_t)524288; // 4 * 131072
  float* catp = qp + 4 * 131072;          // 4 * 131072
  float* ctx  = catp + 4 * 131072;        // 131072
  unsigned short* catb = (unsigned short*)(ctx + 131072);   // 131072 bf16
  unsigned short* hbf0 = catb + 131072;   // 131072 bf16 (layer0 h)
  unsigned short* hbf1 = hbf0 + 131072;   // 131072 bf16 (layer1 h)
  float* numb = G1p;                      // 16*128*1024 (reuses G1p)
  float2* mden = (float2*)G0p;            // 2048 float2 (reuses G0p)

  // 1. LSTM layer 0 gates: BM=64, grid (128,2,3) = 768 blocks (high TLP)
  gemm_mfma<64, 32, 64, 3, 0, 1, 0, 4><<<dim3(128, 2, 3), 256, 0, stream>>>(
      ids, emb, Ev, Ev, h0, Hv, Hv, w_ih0, Ev, w_hh0, Hv, b_ih0, b_hh0,
      G0p, 4 * Hv, 4 * Hv);
  // 2. LSTM layer 0 pointwise (sums 3 partials); h -> hout[0] + bf16 copy
  lstm_pw<3><<<128, 256, 0, stream>>>(G0p, c0, hout, cout, hbf0);
  // 3. LSTM layer 1 gates: BM=64, grid (128,2,4); A1 = bf16 h(layer0)
  gemm_mfma<64, 32, 64, 4, 0, 0, 1, 4><<<dim3(128, 2, 4), 256, 0, stream>>>(
      nullptr, (const float*)hbf0, Hv, Hv, h0 + Bv * Hv, Hv, Hv,
      w_ih1, Hv, w_hh1, Hv, b_ih1, b_hh1, G1p, 4 * Hv, 4 * Hv);
  // 4. LSTM layer 1 pointwise (sums 4 partials) + bf16 copy
  lstm_pw<4><<<128, 256, 0, stream>>>(G1p, c0 + Bv * Hv, hout + Bv * Hv,
                                      cout + Bv * Hv, hbf1);
  // 5. q = rnn @ attn_w (transposed in staging), A1 = bf16 h, 4-way split-K
  gemm_mfma<64, 32, 64, 4, 1, 0, 1, 4><<<dim3(32, 2, 4), 256, 0, stream>>>(
      nullptr, (const float*)hbf1, Hv, Hv, nullptr, 0, 0, attn_w, Hv,
      nullptr, 0, nullptr, nullptr, qp, Hv, Hv);
  // 6. fused scores+softmax-partials+partial-context, 2048 blocks (8/CU)
  attn_part<<<dim3(128, 16), 256, 0, stream>>>(enc, qp, numb, mden);
  // 7. exact chunk recombination -> ctx
  attn_fin<<<128, 256, 0, stream>>>(numb, mden, ctx);
  // 8. concat gates: A1 = bf16 h (seg1), A2 = ctx f32, 4-way split-K
  gemm_mfma<64, 32, 64, 4, 0, 0, 1, 4><<<dim3(32, 2, 4), 256, 0, stream>>>(
      nullptr, (const float*)hbf1, Hv, Hv, ctx, Hv, Hv, concat_w, 2 * Hv,
      concat_w + Hv, 2 * Hv, concat_b, nullptr, catp, Hv, Hv);
  // 9. cat = tanh(sum of partials) -> bf16 (bit-identical to GEMM's cvt)
  finish_cat<<<128, 256, 0, stream>>>(catp, catb);
  // 10. logits: BM=128/BN=64, grid (500,1) -> ONE m-level (out_w read
  //     exactly once), 500 blocks (~2/CU) for bytes-in-flight. A is bf16.
  gemm_mfma<128, 64, 64, 1, 0, 0, 1, 2><<<dim3(500, 1, 1), 256, 0, stream>>>(
      nullptr, (const float*)catb, Hv, Hv, nullptr, 0, 0, out_w, Hv,
      nullptr, 0, out_b, nullptr, logits, Vv, Vv);
}